// Round 3
// baseline (171.967 us; speedup 1.0000x reference)
//
#include <hip/hip_runtime.h>

#define B_  4
#define N_  4096
#define K_  32
#define C_  64
#define D1_ 64
#define D2_ 64
#define DH_ 128
#define PPB 8

typedef short  short8   __attribute__((ext_vector_type(8)));
typedef float  floatx16 __attribute__((ext_vector_type(16)));
typedef unsigned short ushort_t;
typedef unsigned int   uint_t;

__device__ __forceinline__ float bf_lo(uint_t u){ union{uint_t i;float f;} x; x.i = u << 16; return x.f; }
__device__ __forceinline__ float bf_hi(uint_t u){ union{uint_t i;float f;} x; x.i = u & 0xffff0000u; return x.f; }
__device__ __forceinline__ uint_t bf_of(float f){ union{float f;uint_t i;} x; x.f = f; uint_t b = x.i; return (b + 0x7fffu + ((b >> 16) & 1u)) >> 16; }  // RNE
__device__ __forceinline__ uint_t bf_pk(float a, float b){ return bf_of(a) | (bf_of(b) << 16); }

// ---------------------------------------------------------------------------
// Kernel 0: one-shot transforms (unchanged from R2 — correctness-proven).
//  - copy xyz into d_out[0 .. B*N*3)
//  - W_gvT[c][o] = W_gv[o][c]
//  - Bpack: W_h bf16 in MFMA B-fragment order:
//      flat = ((ob*8+c)*64 + l)*8 + j -> W_h[o = ob*32+(l&31)][i = c*16+(l>>5)*8+j]
//  - W_fT[i][c] = W_f[c][i]
// ---------------------------------------------------------------------------
__global__ __launch_bounds__(256) void k_transforms(
    const float* __restrict__ xyz,
    const float* __restrict__ W_gv,
    const float* __restrict__ W_h,
    const float* __restrict__ W_f,
    float* __restrict__ out_xyz,
    float* __restrict__ W_gvT,
    ushort_t* __restrict__ Bpack,
    float* __restrict__ W_fT)
{
    int e = blockIdx.x * 256 + threadIdx.x;
    if (e < B_*N_*3) { out_xyz[e] = xyz[e]; return; }
    e -= B_*N_*3;
    if (e < D2_*C_) { int o = e >> 6, c = e & 63; W_gvT[c*D2_ + o] = W_gv[e]; return; }
    e -= D2_*C_;
    if (e < DH_*(D1_+D2_)) {
        int j = e & 7, l = (e >> 3) & 63, c = (e >> 9) & 7, ob = e >> 12;
        int o = ob*32 + (l & 31);
        int i = c*16 + (l >> 5)*8 + j;
        Bpack[e] = (ushort_t)bf_of(W_h[o*(D1_+D2_) + i]);
        return;
    }
    e -= DH_*(D1_+D2_);
    if (e < C_*DH_) { int i = e >> 6, c = e & 63; W_fT[e] = W_f[c*DH_ + i]; }
}

// ---------------------------------------------------------------------------
// Kernel 1: per-point precompute, 16-point tiles (1024 blocks, 4/CU).
//  GEMM 16n x 64o x 64c (gv), gu computed directly from xyz.
//  Qs  [n][0:64]  = (xyz·Wgu[:, :3])*s_gu + b_gu   fp32
//  Qs  [n][64:128]= Pgv*s_gv + b_gv                fp32
//  Pcat[n][0:64]  = (xyz·Wgu[:, 3:])*s_gu          bf16
//  Pcat[n][64:128]= Pgv*s_gv                       bf16
//  Epilogue thread map (n = t>>4, oq = t&15): 16 consecutive lanes write one
//  row's 256 B (fp32) / 128 B (bf16) fully contiguous — coalesced.
// ---------------------------------------------------------------------------
__global__ __launch_bounds__(256) void k_pre(
    const float* __restrict__ xyz,
    const float* __restrict__ features,
    const float* __restrict__ W_gvT,
    const float* __restrict__ W_gu,
    const float* __restrict__ s_gu, const float* __restrict__ b_gu,
    const float* __restrict__ s_gv, const float* __restrict__ b_gv,
    float* __restrict__ Qs,
    ushort_t* __restrict__ Pcat)
{
    const int b  = blockIdx.x >> 8;
    const int n0 = (blockIdx.x & 255) * 16;
    const int t  = threadIdx.x;

    __shared__ float ftile[64 * 17];   // [c][n], stride 17

    {   // stage: one float4 per thread (64c x 16n)
        const int c = t >> 2, nq = t & 3;
        float4 f4 = *(const float4*)&features[(b*C_ + c)*N_ + n0 + nq*4];
        ftile[c*17 + nq*4 + 0] = f4.x;
        ftile[c*17 + nq*4 + 1] = f4.y;
        ftile[c*17 + nq*4 + 2] = f4.z;
        ftile[c*17 + nq*4 + 3] = f4.w;
    }
    __syncthreads();

    const int n  = t >> 4;       // 0..15
    const int oq = t & 15;       // o-chunk of 4
    const int o0 = oq * 4;

    float acc[4] = {};
    for (int c = 0; c < 64; c++) {
        const float a = ftile[c*17 + n];           // 4-lane broadcast
        const float4 wv = *(const float4*)&W_gvT[c*64 + o0];
        acc[0] = fmaf(a, wv.x, acc[0]);
        acc[1] = fmaf(a, wv.y, acc[1]);
        acc[2] = fmaf(a, wv.z, acc[2]);
        acc[3] = fmaf(a, wv.w, acc[3]);
    }

    const int bn = b*N_ + n0 + n;
    const float x0 = xyz[bn*3+0], x1 = xyz[bn*3+1], x2 = xyz[bn*3+2];

    const float4 sgu = *(const float4*)&s_gu[o0];
    const float4 bgu = *(const float4*)&b_gu[o0];
    const float4 sgv = *(const float4*)&s_gv[o0];
    const float4 bgv = *(const float4*)&b_gv[o0];

    float q[4], r[4];
#pragma unroll
    for (int j = 0; j < 4; j++) {
        const int o = o0 + j;
        q[j] = x0*W_gu[o*6+0] + x1*W_gu[o*6+1] + x2*W_gu[o*6+2];
        r[j] = x0*W_gu[o*6+3] + x1*W_gu[o*6+4] + x2*W_gu[o*6+5];
    }
    // gu half
    float4 qs;
    qs.x = q[0]*sgu.x + bgu.x; qs.y = q[1]*sgu.y + bgu.y;
    qs.z = q[2]*sgu.z + bgu.z; qs.w = q[3]*sgu.w + bgu.w;
    *(float4*)&Qs[bn*128 + o0] = qs;
    uint2 pk;
    pk.x = bf_pk(r[0]*sgu.x, r[1]*sgu.y);
    pk.y = bf_pk(r[2]*sgu.z, r[3]*sgu.w);
    *(uint2*)&Pcat[bn*128 + o0] = pk;
    // gv half
    qs.x = acc[0]*sgv.x + bgv.x; qs.y = acc[1]*sgv.y + bgv.y;
    qs.z = acc[2]*sgv.z + bgv.z; qs.w = acc[3]*sgv.w + bgv.w;
    *(float4*)&Qs[bn*128 + 64 + o0] = qs;
    pk.x = bf_pk(acc[0]*sgv.x, acc[1]*sgv.y);
    pk.y = bf_pk(acc[2]*sgv.z, acc[3]*sgv.w);
    *(uint2*)&Pcat[bn*128 + 64 + o0] = pk;
}

// ---------------------------------------------------------------------------
// Kernel 2: MFMA main. 4 waves; waves pair up: wave w -> (slot = w>>1 of 2
// concurrent points, o-half = w&1). Each wave holds 2 B-fragment sets and
// issues 2 MFMAs per A-chunk read (halves fuse-read redundancy vs R2).
// fuse stride 66 words -> A-chunk reads are 8 B-aligned ds_read_b64, 2-way.
// idx delivered by __shfl (no LDS array, 2 barriers per 2 points).
// ---------------------------------------------------------------------------
__global__ __launch_bounds__(256) void k_main(
    const int*      __restrict__ idx,
    const float*    __restrict__ Qs,
    const ushort_t* __restrict__ Pcat,
    const ushort_t* __restrict__ Bpack,
    const float*    __restrict__ s_h, const float* __restrict__ b_h,
    float* __restrict__ Pool)
{
    const int t    = threadIdx.x;
    const int w    = t >> 6;
    const int lane = t & 63;
    const int m    = lane & 31;
    const int hh   = lane >> 5;
    const int slot = w >> 1;     // phase-2 point slot
    const int oh   = w & 1;      // phase-2 o-half (o in [oh*64, oh*64+64))

    __shared__ uint_t fuse[2 * 32 * 66];   // [slot][row][word]

    short8 Bf[2][8];
#pragma unroll
    for (int ob = 0; ob < 2; ob++)
#pragma unroll
        for (int c = 0; c < 8; c++)
            Bf[ob][c] = *(const short8*)&Bpack[(((oh*2 + ob)*8 + c)*64 + lane)*8];

    float sh[2], bh[2];
#pragma unroll
    for (int ob = 0; ob < 2; ob++) {
        sh[ob] = s_h[(oh*2 + ob)*32 + m];
        bh[ob] = b_h[(oh*2 + ob)*32 + m];
    }

    for (int rr = 0; rr < PPB/2; rr++) {
        const int bn0   = blockIdx.x * PPB + rr*2;      // slots bn0, bn0+1
        const int base0 = bn0 & ~(N_ - 1);              // b*N_ (PPB | N_)

        // lane hh holds idx row for slot hh, neighbor m
        const int jall = idx[((bn0 + hh) & (N_-1))*K_ + m];
        float2 q2[2];
        q2[0] = *(const float2*)&Qs[(bn0+0)*128 + lane*2];
        q2[1] = *(const float2*)&Qs[(bn0+1)*128 + lane*2];

        __syncthreads();   // prev round's fuse fully consumed
#pragma unroll
        for (int it = 0; it < 16; it++) {
            const int rs  = it*4 + w;          // 0..63 over 2 slots x 32 rows
            const int sl  = rs >> 5, row = rs & 31;
            const int j   = __shfl(jall, rs);  // wave-uniform
            const uint_t rp = *(const uint_t*)&Pcat[(base0 + j)*128 + lane*2];
            const float2 q  = q2[sl];
            const float v0 = fmaxf(q.x + bf_lo(rp), 0.f);
            const float v1 = fmaxf(q.y + bf_hi(rp), 0.f);
            fuse[sl*2112 + row*66 + lane] = bf_pk(v0, v1);
        }
        __syncthreads();

        floatx16 acc0 = {}, acc1 = {};
#pragma unroll
        for (int c = 0; c < 8; c++) {
            const int wb = slot*2112 + m*66 + c*8 + hh*4;
            union { uint_t u[4]; short8 s; } av;
            *(uint2*)&av.u[0] = *(const uint2*)&fuse[wb];
            *(uint2*)&av.u[2] = *(const uint2*)&fuse[wb + 2];
            acc0 = __builtin_amdgcn_mfma_f32_32x32x16_bf16(av.s, Bf[0][c], acc0, 0, 0, 0);
            acc1 = __builtin_amdgcn_mfma_f32_32x32x16_bf16(av.s, Bf[1][c], acc1, 0, 0, 0);
        }

        const int bnp = bn0 + slot;
        float v0 = 0.f, v1 = 0.f;
#pragma unroll
        for (int rg = 0; rg < 16; rg++) {
            v0 += fmaxf(acc0[rg]*sh[0] + bh[0], 0.f);
            v1 += fmaxf(acc1[rg]*sh[1] + bh[1], 0.f);
        }
        v0 += __shfl_xor(v0, 32);
        v1 += __shfl_xor(v1, 32);
        if (hh == 0) {
            Pool[bnp*128 + (oh*2+0)*32 + m] = v0;
            Pool[bnp*128 + (oh*2+1)*32 + m] = v1;
        }
    }
}

// ---------------------------------------------------------------------------
// Kernel 3: f layer + residual, 16-point tiles (1024 blocks, 4/CU).
//  GEMM in (n, c-chunk) layout; out-tile restaged via LDS so global writes
//  are c-major coalesced (64 B per 4-lane group, matching features layout).
// ---------------------------------------------------------------------------
__global__ __launch_bounds__(256) void k_post(
    const float* __restrict__ Pool,
    const float* __restrict__ W_fT,
    const float* __restrict__ s_f, const float* __restrict__ b_f,
    const float* __restrict__ features,
    float* __restrict__ outF)
{
    const int b   = blockIdx.x >> 8;
    const int n0  = (blockIdx.x & 255) * 16;
    const int t   = threadIdx.x;
    const int bn0 = b*N_ + n0;

    __shared__ float pt[16 * 132];   // [n][i], stride 132 (16B-aligned rows)
    __shared__ float ot[64 * 17];    // [c][n], stride 17

    {   // stage Pool tile: 2 float4 per thread, fully coalesced
        const int n = t >> 4, iq = t & 15;
        float4 p0 = *(const float4*)&Pool[(bn0 + n)*128 + iq*8];
        float4 p1 = *(const float4*)&Pool[(bn0 + n)*128 + iq*8 + 4];
        *(float4*)&pt[n*132 + iq*8]     = p0;
        *(float4*)&pt[n*132 + iq*8 + 4] = p1;
    }
    __syncthreads();

    const int n  = t >> 4;     // 0..15
    const int cq = t & 15;     // c-chunk of 4
    const int c0 = cq * 4;

    float acc[4] = {};
    for (int i = 0; i < 128; i++) {
        const float p = pt[n*132 + i];             // broadcast
        const float4 wv = *(const float4*)&W_fT[i*64 + c0];
        acc[0] = fmaf(p, wv.x, acc[0]);
        acc[1] = fmaf(p, wv.y, acc[1]);
        acc[2] = fmaf(p, wv.z, acc[2]);
        acc[3] = fmaf(p, wv.w, acc[3]);
    }
    const float4 sf = *(const float4*)&s_f[c0];
    const float4 bf = *(const float4*)&b_f[c0];
    const float inv_k = 1.f / (float)K_;
    ot[(c0+0)*17 + n] = fmaxf(acc[0]*inv_k*sf.x + bf.x, 0.f);
    ot[(c0+1)*17 + n] = fmaxf(acc[1]*inv_k*sf.y + bf.y, 0.f);
    ot[(c0+2)*17 + n] = fmaxf(acc[2]*inv_k*sf.z + bf.z, 0.f);
    ot[(c0+3)*17 + n] = fmaxf(acc[3]*inv_k*sf.w + bf.w, 0.f);
    __syncthreads();

    {   // write out c-major: thread (c = t>>2, nq = t&3) -> float4
        const int c = t >> 2, nq = t & 3;
        const float4 fr = *(const float4*)&features[(b*C_ + c)*N_ + n0 + nq*4];
        float4 ov;
        ov.x = ot[c*17 + nq*4 + 0] + fr.x;
        ov.y = ot[c*17 + nq*4 + 1] + fr.y;
        ov.z = ot[c*17 + nq*4 + 2] + fr.z;
        ov.w = ot[c*17 + nq*4 + 3] + fr.w;
        *(float4*)&outF[(b*C_ + c)*N_ + n0 + nq*4] = ov;
    }
}

// ---------------------------------------------------------------------------
extern "C" void kernel_launch(void* const* d_in, const int* in_sizes, int n_in,
                              void* d_out, int out_size, void* d_ws, size_t ws_size,
                              hipStream_t stream)
{
    const float* xyz      = (const float*)d_in[0];
    const float* features = (const float*)d_in[1];
    const int*   idx      = (const int*)  d_in[2];
    const float* W_gu     = (const float*)d_in[3];
    const float* s_gu     = (const float*)d_in[4];
    const float* b_gu     = (const float*)d_in[5];
    const float* W_gv     = (const float*)d_in[6];
    const float* s_gv     = (const float*)d_in[7];
    const float* b_gv     = (const float*)d_in[8];
    const float* W_h      = (const float*)d_in[9];
    const float* s_h      = (const float*)d_in[10];
    const float* b_h      = (const float*)d_in[11];
    const float* W_f      = (const float*)d_in[12];
    const float* s_f      = (const float*)d_in[13];
    const float* b_f      = (const float*)d_in[14];

    float* out  = (float*)d_out;          // tuple: xyz first, then out
    float* outF = out + B_*N_*3;

    // workspace carve (~20.1 MB)
    char* wp = (char*)d_ws;
    float*    Qs    = (float*)wp;    wp += (size_t)B_*N_*128*4;   // 8 MB
    float*    Pool  = (float*)wp;    wp += (size_t)B_*N_*128*4;   // 8 MB
    ushort_t* Pcat  = (ushort_t*)wp; wp += (size_t)B_*N_*128*2;   // 4 MB
    float*    W_gvT = (float*)wp;    wp += D2_*C_*4;
    ushort_t* Bpack = (ushort_t*)wp; wp += DH_*(D1_+D2_)*2;
    float*    W_fT  = (float*)wp;    wp += C_*DH_*4;

    k_transforms<<<304, 256, 0, stream>>>(xyz, W_gv, W_h, W_f, out, W_gvT, Bpack, W_fT);
    k_pre<<<B_*(N_/16), 256, 0, stream>>>(xyz, features, W_gvT, W_gu,
                                          s_gu, b_gu, s_gv, b_gv, Qs, Pcat);
    k_main<<<(B_*N_)/PPB, 256, 0, stream>>>(idx, Qs, Pcat, Bpack, s_h, b_h, Pool);
    k_post<<<B_*(N_/16), 256, 0, stream>>>(Pool, W_fT, s_f, b_f, features, outF);
}

// Round 5
// 137.878 us; speedup vs baseline: 1.2472x; 1.2472x over previous
//
#include <hip/hip_runtime.h>

#define B_  4
#define N_  4096
#define K_  32
#define C_  64
#define DH_ 128
#define PPB 16

typedef _Float16 half2v __attribute__((ext_vector_type(2)));
typedef _Float16 half8  __attribute__((ext_vector_type(8)));
typedef __fp16   fp16x2 __attribute__((ext_vector_type(2)));
typedef float  floatx16 __attribute__((ext_vector_type(16)));
typedef unsigned int uint_t;

union HU { half2v h; uint_t u; };
union HU2 { fp16x2 h; uint_t u; };

__device__ __forceinline__ uint_t pk2(float a, float b) {
    HU2 x; x.h = __builtin_amdgcn_cvt_pkrtz(a, b);   // v_cvt_pkrtz_f16_f32
    return x.u;
}

// ---------------------------------------------------------------------------
// Kernel 0: xyz copy (output 0) + Bpack = (W_h * s_h) as f16 in MFMA B-frag
// order: flat = ((ob*8+c)*64+l)*8+j -> W_h[o=ob*32+(l&31)][i=c*16+(l>>5)*8+j].
// 49152 + 16384 = 65536 = 256*256.
// ---------------------------------------------------------------------------
__global__ __launch_bounds__(256) void k_transforms(
    const float* __restrict__ xyz,
    const float* __restrict__ W_h,
    const float* __restrict__ s_h,
    float* __restrict__ out_xyz,
    _Float16* __restrict__ Bpack)
{
    int e = blockIdx.x * 256 + threadIdx.x;
    if (e < B_*N_*3) { out_xyz[e] = xyz[e]; return; }
    e -= B_*N_*3;
    int j = e & 7, l = (e >> 3) & 63, c = (e >> 9) & 7, ob = e >> 12;
    int o = ob*32 + (l & 31);
    int i = c*16 + (l >> 5)*8 + j;
    Bpack[e] = (_Float16)(W_h[o*DH_ + i] * s_h[o]);
}

// ---------------------------------------------------------------------------
// Kernel 1: per-point precompute, 64-pt tiles (256 blocks).
//  Pgv[n][o] = feats[n]·W_gv^T  (64x64x64 GEMM, both operands LDS-staged)
//  QsH [n] (f16x2 words 0..31 gu | 32..63 gv): center half with affine folded
//  PcatH[n] (same layout): neighbor half with scale folded
//  => fuse[k][i] = relu(QsH[n][i] + PcatH[idx[n][k]][i])  in f16
// ---------------------------------------------------------------------------
__global__ __launch_bounds__(256) void k_pre(
    const float* __restrict__ xyz,
    const float* __restrict__ features,
    const float* __restrict__ W_gv,
    const float* __restrict__ W_gu,
    const float* __restrict__ s_gu, const float* __restrict__ b_gu,
    const float* __restrict__ s_gv, const float* __restrict__ b_gv,
    uint_t* __restrict__ QsH,
    uint_t* __restrict__ PcatH)
{
    const int b  = blockIdx.x >> 6;
    const int n0 = (blockIdx.x & 63) * 64;
    const int t  = threadIdx.x;

    __shared__ __align__(16) float ftile[64 * 66];   // [c][n], stride 66
    __shared__ __align__(16) float wtile[64 * 68];   // [c][o], stride 68 (16B-aligned)
    __shared__ float xs[192];
    __shared__ float wgu[384];

    const int nn = t & 63, cq = t >> 6;
#pragma unroll
    for (int r = 0; r < 16; r++) {
        int c = cq * 16 + r;
        ftile[c*66 + nn] = features[(b*C_ + c)*N_ + n0 + nn];
    }
    for (int e = t; e < 64*64; e += 256) {
        int o = e >> 6, c = e & 63;
        wtile[c*68 + o] = W_gv[e];
    }
    if (t < 192) xs[t] = xyz[(b*N_ + n0)*3 + t];
    if (t < 128) { wgu[t] = W_gu[t]; wgu[t+128] = W_gu[t+128]; wgu[t+256] = W_gu[t+256]; }
    __syncthreads();

    const int nt = t & 31, ot = t >> 5;      // 32 n-tiles x 8 o-chunks
    const int nl0 = nt * 2, o0 = ot * 8;

    float acc[2][8] = {};
    for (int c = 0; c < 64; c++) {
        const float2 a = *(const float2*)&ftile[c*66 + nl0];
        float wv[8];
        *(float4*)&wv[0] = *(const float4*)&wtile[c*68 + o0];
        *(float4*)&wv[4] = *(const float4*)&wtile[c*68 + o0 + 4];
#pragma unroll
        for (int oo = 0; oo < 8; oo++) {
            acc[0][oo] = fmaf(a.x, wv[oo], acc[0][oo]);
            acc[1][oo] = fmaf(a.y, wv[oo], acc[1][oo]);
        }
    }

    float sgu[8], bgu[8], sgv[8], bgv[8];
    *(float4*)&sgu[0] = *(const float4*)&s_gu[o0]; *(float4*)&sgu[4] = *(const float4*)&s_gu[o0+4];
    *(float4*)&bgu[0] = *(const float4*)&b_gu[o0]; *(float4*)&bgu[4] = *(const float4*)&b_gu[o0+4];
    *(float4*)&sgv[0] = *(const float4*)&s_gv[o0]; *(float4*)&sgv[4] = *(const float4*)&s_gv[o0+4];
    *(float4*)&bgv[0] = *(const float4*)&b_gv[o0]; *(float4*)&bgv[4] = *(const float4*)&b_gv[o0+4];

#pragma unroll
    for (int kk = 0; kk < 2; kk++) {
        const int nl = nl0 + kk;
        const int bn = b*N_ + n0 + nl;
        const float x0 = xs[nl*3], x1 = xs[nl*3+1], x2 = xs[nl*3+2];
        float qv[8], rv[8];
#pragma unroll
        for (int oo = 0; oo < 8; oo++) {
            const int o = o0 + oo;
            qv[oo] = x0*wgu[o*6+0] + x1*wgu[o*6+1] + x2*wgu[o*6+2];
            rv[oo] = x0*wgu[o*6+3] + x1*wgu[o*6+4] + x2*wgu[o*6+5];
        }
        uint4 qa, pa;
        // gu half (words 0..31)
        qa.x = pk2(qv[0]*sgu[0]+bgu[0], qv[1]*sgu[1]+bgu[1]);
        qa.y = pk2(qv[2]*sgu[2]+bgu[2], qv[3]*sgu[3]+bgu[3]);
        qa.z = pk2(qv[4]*sgu[4]+bgu[4], qv[5]*sgu[5]+bgu[5]);
        qa.w = pk2(qv[6]*sgu[6]+bgu[6], qv[7]*sgu[7]+bgu[7]);
        pa.x = pk2(rv[0]*sgu[0], rv[1]*sgu[1]);
        pa.y = pk2(rv[2]*sgu[2], rv[3]*sgu[3]);
        pa.z = pk2(rv[4]*sgu[4], rv[5]*sgu[5]);
        pa.w = pk2(rv[6]*sgu[6], rv[7]*sgu[7]);
        *(uint4*)&QsH  [bn*64 + ot*4] = qa;
        *(uint4*)&PcatH[bn*64 + ot*4] = pa;
        // gv half (words 32..63)
        qa.x = pk2(acc[kk][0]*sgv[0]+bgv[0], acc[kk][1]*sgv[1]+bgv[1]);
        qa.y = pk2(acc[kk][2]*sgv[2]+bgv[2], acc[kk][3]*sgv[3]+bgv[3]);
        qa.z = pk2(acc[kk][4]*sgv[4]+bgv[4], acc[kk][5]*sgv[5]+bgv[5]);
        qa.w = pk2(acc[kk][6]*sgv[6]+bgv[6], acc[kk][7]*sgv[7]+bgv[7]);
        pa.x = pk2(acc[kk][0]*sgv[0], acc[kk][1]*sgv[1]);
        pa.y = pk2(acc[kk][2]*sgv[2], acc[kk][3]*sgv[3]);
        pa.z = pk2(acc[kk][4]*sgv[4], acc[kk][5]*sgv[5]);
        pa.w = pk2(acc[kk][6]*sgv[6], acc[kk][7]*sgv[7]);
        *(uint4*)&QsH  [bn*64 + 32 + ot*4] = qa;
        *(uint4*)&PcatH[bn*64 + 32 + ot*4] = pa;
    }
}

// ---------------------------------------------------------------------------
// Kernel 2: fused main + f-layer. Block = 256 thr (4 waves), PPB=16 points.
//  Per round (2 points): fuse build in pk-f16 (2 inst / 2 elems), then wave
//  (slot=w>>1, oh=w&1) does 2x mfma_f32_32x32x16_f16 per A-chunk against
//  resident W_h fragments (s_h pre-folded); relu+pool -> pooledAll in LDS.
//  Final phase: f layer (64 c x 16 n) + residual, 64B-coalesced store.
// ---------------------------------------------------------------------------
__global__ __launch_bounds__(256) void k_main(
    const int*      __restrict__ idx,
    const uint_t*   __restrict__ QsH,
    const uint_t*   __restrict__ PcatH,
    const _Float16* __restrict__ Bpack,
    const float*    __restrict__ b_h,
    const float*    __restrict__ W_f,
    const float*    __restrict__ s_f, const float* __restrict__ b_f,
    const float*    __restrict__ features,
    float* __restrict__ outF)
{
    const int t    = threadIdx.x;
    const int w    = t >> 6;
    const int lane = t & 63;
    const int m    = lane & 31;
    const int hh   = lane >> 5;
    const int slot = w >> 1;     // MFMA-phase point slot
    const int oh   = w & 1;      // MFMA-phase o-half

    __shared__ uint_t fuse[2 * 32 * 66];        // [slot][row][word]
    __shared__ __align__(16) float pooledAll[PPB * 136];

    half8 Bf[2][8];
#pragma unroll
    for (int ob = 0; ob < 2; ob++)
#pragma unroll
        for (int c = 0; c < 8; c++)
            Bf[ob][c] = *(const half8*)&Bpack[(((oh*2 + ob)*8 + c)*64 + lane)*8];

    const float bh0 = b_h[(oh*2+0)*32 + m];
    const float bh1 = b_h[(oh*2+1)*32 + m];

    const int bnb   = blockIdx.x * PPB;
    const int base0 = bnb & ~(N_ - 1);           // b*N_
    const half2v zero2 = {(_Float16)0.f, (_Float16)0.f};

    for (int rr = 0; rr < PPB/2; rr++) {
        const int bn0 = bnb + rr*2;
        // lane-half hh holds idx row for point bn0+hh, neighbor m
        const int jall = idx[((bn0 + hh) & (N_-1))*K_ + m];
        const uint_t qw0 = QsH[(bn0+0)*64 + lane];
        const uint_t qw1 = QsH[(bn0+1)*64 + lane];

        __syncthreads();   // prev round's fuse fully consumed
#pragma unroll
        for (int it = 0; it < 16; it++) {
            const int rs  = it*4 + w;            // 0..63: 2 slots x 32 rows
            const int sl  = rs >> 5, row = rs & 31;
            const int j   = __shfl(jall, rs);    // wave-uniform
            const uint_t rp = PcatH[(base0 + j)*64 + lane];
            HU a, p; a.u = sl ? qw1 : qw0; p.u = rp;
            half2v v = a.h + p.h;                // v_pk_add_f16
            v = __builtin_elementwise_max(v, zero2);   // v_pk_max_f16
            HU o2; o2.h = v;
            fuse[sl*2112 + row*66 + lane] = o2.u;
        }
        __syncthreads();

        floatx16 acc0 = {}, acc1 = {};
#pragma unroll
        for (int c = 0; c < 8; c++) {
            const int wb = slot*2112 + m*66 + c*8 + hh*4;
            union { uint_t u[4]; half8 h; } av;
            *(uint2*)&av.u[0] = *(const uint2*)&fuse[wb];
            *(uint2*)&av.u[2] = *(const uint2*)&fuse[wb + 2];
            acc0 = __builtin_amdgcn_mfma_f32_32x32x16_f16(av.h, Bf[0][c], acc0, 0, 0, 0);
            acc1 = __builtin_amdgcn_mfma_f32_32x32x16_f16(av.h, Bf[1][c], acc1, 0, 0, 0);
        }

        float v0 = 0.f, v1 = 0.f;
#pragma unroll
        for (int rg = 0; rg < 16; rg++) {
            v0 += fmaxf(acc0[rg] + bh0, 0.f);
            v1 += fmaxf(acc1[rg] + bh1, 0.f);
        }
        v0 += __shfl_xor(v0, 32);
        v1 += __shfl_xor(v1, 32);
        const int nl = rr*2 + slot;
        if (hh == 0) {
            pooledAll[nl*136 + (oh*2+0)*32 + m] = v0;
            pooledAll[nl*136 + (oh*2+1)*32 + m] = v1;
        }
    }
    __syncthreads();

    // ---- f layer + residual for the block's 16 points ----
    const int b  = bnb >> 12;
    const int n0 = bnb & (N_ - 1);
    const int c  = t >> 2;       // 0..63
    const int nq = t & 3;        // 4 n's per thread

    float acc[4] = {};
    for (int i0 = 0; i0 < DH_; i0 += 4) {
        const float4 wv = *(const float4*)&W_f[c*DH_ + i0];
#pragma unroll
        for (int r = 0; r < 4; r++) {
            const float4 p = *(const float4*)&pooledAll[(nq*4 + r)*136 + i0];
            acc[r] += wv.x*p.x + wv.y*p.y + wv.z*p.z + wv.w*p.w;
        }
    }
    const float sfc = s_f[c] * (1.f/(float)K_);
    const float bfc = b_f[c];
    const float4 fr = *(const float4*)&features[(b*C_ + c)*N_ + n0 + nq*4];
    float4 ov;
    ov.x = fmaxf(acc[0]*sfc + bfc, 0.f) + fr.x;
    ov.y = fmaxf(acc[1]*sfc + bfc, 0.f) + fr.y;
    ov.z = fmaxf(acc[2]*sfc + bfc, 0.f) + fr.z;
    ov.w = fmaxf(acc[3]*sfc + bfc, 0.f) + fr.w;
    *(float4*)&outF[(b*C_ + c)*N_ + n0 + nq*4] = ov;
}

// ---------------------------------------------------------------------------
extern "C" void kernel_launch(void* const* d_in, const int* in_sizes, int n_in,
                              void* d_out, int out_size, void* d_ws, size_t ws_size,
                              hipStream_t stream)
{
    const float* xyz      = (const float*)d_in[0];
    const float* features = (const float*)d_in[1];
    const int*   idx      = (const int*)  d_in[2];
    const float* W_gu     = (const float*)d_in[3];
    const float* s_gu     = (const float*)d_in[4];
    const float* b_gu     = (const float*)d_in[5];
    const float* W_gv     = (const float*)d_in[6];
    const float* s_gv     = (const float*)d_in[7];
    const float* b_gv     = (const float*)d_in[8];
    const float* W_h      = (const float*)d_in[9];
    const float* s_h      = (const float*)d_in[10];
    const float* b_h      = (const float*)d_in[11];
    const float* W_f      = (const float*)d_in[12];
    const float* s_f      = (const float*)d_in[13];
    const float* b_f      = (const float*)d_in[14];

    float* out  = (float*)d_out;          // tuple: xyz first, then out
    float* outF = out + B_*N_*3;

    // workspace carve (~8.1 MB)
    char* wp = (char*)d_ws;
    uint_t*   QsH   = (uint_t*)wp;   wp += (size_t)B_*N_*64*4;    // 4 MB
    uint_t*   PcatH = (uint_t*)wp;   wp += (size_t)B_*N_*64*4;    // 4 MB
    _Float16* Bpack = (_Float16*)wp; wp += DH_*(DH_)*2;           // 32 KB

    k_transforms<<<256, 256, 0, stream>>>(xyz, W_h, s_h, out, Bpack);
    k_pre<<<B_*(N_/64), 256, 0, stream>>>(xyz, features, W_gv, W_gu,
                                          s_gu, b_gu, s_gv, b_gv, QsH, PcatH);
    k_main<<<(B_*N_)/PPB, 256, 0, stream>>>(idx, QsH, PcatH, Bpack, b_h,
                                            W_f, s_f, b_f, features, outF);
}